// Round 8
// baseline (262.044 us; speedup 1.0000x reference)
//
#include <hip/hip_runtime.h>

// Problem constants
#define S_LEN 256
#define B_SZ  128
#define M_ROWS (S_LEN * B_SZ)          // 32768

typedef __attribute__((ext_vector_type(8))) short bf16x8;
typedef __attribute__((ext_vector_type(4))) float f32x4;

__device__ __forceinline__ unsigned short f2bf(float x) {
    unsigned u = __float_as_uint(x);
    unsigned r = (u + 0x7fffu + ((u >> 16) & 1u)) >> 16;   // RNE
    return (unsigned short)r;
}

__device__ __forceinline__ void gl_lds16(const void* g, void* l) {
    __builtin_amdgcn_global_load_lds(
        (const __attribute__((address_space(1))) unsigned int*)g,
        (__attribute__((address_space(3))) unsigned int*)l,
        16, 0, 0);
}

// ---------------- Pass 1: seq f32 -> bf16 ----------------
__global__ __launch_bounds__(256) void convert_seq(const float* __restrict__ in,
                                                   unsigned short* __restrict__ out,
                                                   long n4) {
    long i = (long)blockIdx.x * blockDim.x + threadIdx.x;
    long stride = (long)gridDim.x * blockDim.x;
    for (; i < n4; i += stride) {
        float4 v = ((const float4*)in)[i];
        ushort4 o;
        o.x = f2bf(v.x); o.y = f2bf(v.y); o.z = f2bf(v.z); o.w = f2bf(v.w);
        ((ushort4*)out)[i] = o;
    }
}

// ---------------- Pass 2: f1,f2 f32 -> bf16 (layer-major) ----------------
__global__ __launch_bounds__(256) void convert_f(const float* __restrict__ f1,
                                                 const float* __restrict__ f2,
                                                 unsigned short* __restrict__ out) {
    int g = blockIdx.x * 256 + threadIdx.x;            // 0..65535 float4 groups
    float4 v = (g < 32768) ? ((const float4*)f1)[g] : ((const float4*)f2)[g - 32768];
    ushort4 o;
    o.x = f2bf(v.x); o.y = f2bf(v.y); o.z = f2bf(v.z); o.w = f2bf(v.w);
    ((ushort4*)out)[g] = o;
}

// ---------------- Pass 3: W [2048][1024] f32 -> Wt [2][1024][2048] bf16 ----------------
__global__ __launch_bounds__(256) void transpose_w(const float* __restrict__ W11,
                                                   const float* __restrict__ W12,
                                                   unsigned short* __restrict__ Wt) {
    const int nt = blockIdx.x, kt = blockIdx.y, layer = blockIdx.z;
    const float* W = layer ? W12 : W11;
    __shared__ float T[64][65];
    const int c = threadIdx.x & 63, r4 = threadIdx.x >> 6;
    const int k0 = kt * 64, n0 = nt * 64;
    #pragma unroll
    for (int p = 0; p < 16; ++p) {
        int r = p * 4 + r4;
        T[r][c] = W[(size_t)(k0 + r) * 1024 + n0 + c];
    }
    __syncthreads();
    unsigned short* Wl = Wt + (size_t)layer * 1024 * 2048;
    #pragma unroll
    for (int p = 0; p < 16; ++p) {
        int n = p * 4 + r4;
        Wl[(size_t)(n0 + n) * 2048 + k0 + c] = f2bf(T[c][n]);
    }
}

// ---------------- Pass 4: c[layer][b][h] = f@W[1024:] + bias  (MFMA 128x128 tile) ----------------
__global__ __launch_bounds__(256) void c_precompute(const unsigned short* __restrict__ fbf, // [2][128][1024]
                                                    const unsigned short* __restrict__ Wt,  // [2][1024][2048]
                                                    const float* __restrict__ b11,
                                                    const float* __restrict__ b12,
                                                    float* __restrict__ cbuf) {            // [2][128][1024]
    __shared__ char smem[32768];
    unsigned short* ldsA = (unsigned short*)smem;            // [128][64]
    unsigned short* ldsB = (unsigned short*)(smem + 16384);  // [128][64]
    const int n0 = blockIdx.x * 128;
    const int layer = blockIdx.y;
    const int tid = threadIdx.x;
    const int w = tid >> 6, l = tid & 63;
    const int wm = w >> 1, wn = w & 1;
    const int lr = l & 15, lg = l >> 4;
    const unsigned short* Af = fbf + (size_t)layer * 128 * 1024;
    const unsigned short* Wl = Wt + (size_t)layer * 1024 * 2048;
    const float* bias = layer ? b12 : b11;

    f32x4 acc[4][4];
    #pragma unroll
    for (int i = 0; i < 4; ++i)
        #pragma unroll
        for (int j = 0; j < 4; ++j)
            #pragma unroll
            for (int e = 0; e < 4; ++e) acc[i][j][e] = 0.f;

    for (int kk = 0; kk < 1024; kk += 64) {
        __syncthreads();
        #pragma unroll
        for (int c = 0; c < 4; ++c) {
            int o = w * 4096 + c * 1024;
            int ob = o + l * 16;
            int row = ob >> 7, kb = ob & 127;
            gl_lds16((const char*)Af + ((size_t)row * 1024 + kk) * 2 + kb, (char*)ldsA + o);
            gl_lds16((const char*)Wl + ((size_t)(n0 + row) * 2048 + 1024 + kk) * 2 + kb, (char*)ldsB + o);
        }
        __syncthreads();
        #pragma unroll
        for (int ks = 0; ks < 2; ++ks) {
            bf16x8 av[4], bv[4];
            #pragma unroll
            for (int i = 0; i < 4; ++i) {
                av[i] = *(const bf16x8*)(ldsA + (wm * 64 + i * 16 + lr) * 64 + ks * 32 + lg * 8);
                bv[i] = *(const bf16x8*)(ldsB + (wn * 64 + i * 16 + lr) * 64 + ks * 32 + lg * 8);
            }
            #pragma unroll
            for (int i = 0; i < 4; ++i)
                #pragma unroll
                for (int j = 0; j < 4; ++j)
                    acc[i][j] = __builtin_amdgcn_mfma_f32_16x16x32_bf16(av[i], bv[j], acc[i][j], 0, 0, 0);
        }
    }
    float* cl = cbuf + (size_t)layer * 128 * 1024;
    #pragma unroll
    for (int i = 0; i < 4; ++i)
        #pragma unroll
        for (int j = 0; j < 4; ++j)
            #pragma unroll
            for (int q = 0; q < 4; ++q) {
                int rr = wm * 64 + i * 16 + lg * 4 + q;
                int hc = n0 + wn * 64 + j * 16 + lr;
                cl[(size_t)rr * 1024 + hc] = acc[i][j][q] + bias[hc];
            }
}

// ================= Pass 5: main fused GEMM =================
// 256x256 tile, BK=64, 8 waves (wave-tile 128x64), 2 LDS bufs (128 KB, 1 blk/CU).
// REGISTER-PREFETCH pipeline: per K-tile t
//   { read sub1 frags | MFMA sub0 | lgkm(0)+vmcnt(0) | barrier
//     | STAGE(t+2 -> buf[t&1]) | read tile(t+1) sub0 frags | MFMA sub1 }
// MFMA never waits on LDS in steady state: its fragments were loaded one
// sub-step (~600 cyc) earlier and drained by the pre-barrier lgkm(0).
// vmcnt(0) pre-barrier waits stage(t+1), issued a full K-tile earlier.
// One barrier per K-tile (16 total).
// LDS tile [256 rows][128 B]; swizzle involution x ^= ((x>>3)&0x70)
// (= R4's verified conflict-free form for 128-B rows).
// XCD decode: concurrent set per XCD = 4 A-tiles (2 MB) + 8 B-slices (4 MB).

__global__ __launch_bounds__(512, 2) void fused_main(const unsigned short* __restrict__ Abf, // [32768][1024] bf16
                                                     const unsigned short* __restrict__ Wt,  // [2][1024][2048] bf16
                                                     const float* __restrict__ cbuf,         // [2][128][1024]
                                                     const float* __restrict__ W21,
                                                     const float* __restrict__ W22,
                                                     float* __restrict__ sbufp) {            // [8][32768]
    __shared__ char smem[131072];   // 2 bufs x (A 32K + B 32K)
    const int bid = blockIdx.x;
    const int xcd = bid & 7;
    const int idx = bid >> 3;                    // 0..127
    const int mtq = (idx & 3) + 4 * (idx >> 5);  // 0..15
    const int g   = (idx >> 2) & 7;              // layer*4 + nt
    const int mt  = xcd + 8 * mtq;               // 0..127
    const int layer = g >> 2;
    const int nt    = g & 3;
    const int n0 = nt * 256;

    const int tid = threadIdx.x;
    const int w = tid >> 6, l = tid & 63;
    const int wm = w >> 2, wn = w & 3;  // 2 M-halves x 4 N-quarters (wave tile 128x64)
    const int lr = l & 15, lg = l >> 4;

    const char* Ag = (const char*)Abf + (size_t)mt * 256 * 2048;                          // row stride 2048 B
    const char* Bg = (const char*)(Wt + (size_t)layer * 1024 * 2048) + (size_t)n0 * 4096; // row stride 4096 B

    // staging: 64 KB per K-tile, 512 thr x 16 B x 4 rounds each for A and B.
    // linear dest dloc = r*8192 + tid*16; global src inverse-swizzled.
    const int dloc = tid * 16;
    const int gsw  = dloc ^ ((dloc >> 3) & 0x70);
    const int rowS = gsw >> 7, colS = gsw & 127;
    const char* srcA = Ag + (size_t)rowS * 2048 + colS;
    const char* srcB = Bg + (size_t)rowS * 4096 + colS;
    const int dstT = w * 1024;

    // fragment LDS addressing (per-lane, loop-invariant)
    const int xr = (lr & 7) << 4;
    const int colx0 = (lg * 16) ^ xr;
    const int colx1 = (lg * 16 + 64) ^ xr;
    const int baseA = (wm * 128 + lr) * 128;
    const int baseB = 32768 + (wn * 64 + lr) * 128;

    f32x4 acc[8][4];
    #pragma unroll
    for (int i = 0; i < 8; ++i)
        #pragma unroll
        for (int j = 0; j < 4; ++j)
            #pragma unroll
            for (int e = 0; e < 4; ++e) acc[i][j][e] = 0.f;

    bf16x8 fA0[8], fA1[8], fB0[4], fB1[4];

#define STAGE(t) do {                                                   \
        char* d_ = smem + ((t) & 1) * 65536;                            \
        const char* a_ = srcA + (size_t)(t) * 128;                      \
        const char* b_ = srcB + (size_t)(t) * 128;                      \
        _Pragma("unroll")                                               \
        for (int r_ = 0; r_ < 4; ++r_) {                                \
            gl_lds16(a_ + r_ * 131072, d_ + r_ * 8192 + dstT);          \
            gl_lds16(b_ + r_ * 262144, d_ + 32768 + r_ * 8192 + dstT);  \
        }                                                               \
    } while (0)

#define LOADF(sA, sB, bo, cx) do {                                      \
        const char* ba_ = smem + (bo) + baseA;                          \
        const char* bb_ = smem + (bo) + baseB;                          \
        _Pragma("unroll")                                               \
        for (int i_ = 0; i_ < 8; ++i_) sA[i_] = *(const bf16x8*)(ba_ + i_ * 2048 + (cx)); \
        _Pragma("unroll")                                               \
        for (int j_ = 0; j_ < 4; ++j_) sB[j_] = *(const bf16x8*)(bb_ + j_ * 2048 + (cx)); \
    } while (0)

#define MF(sA, sB) do {                                                 \
        _Pragma("unroll")                                               \
        for (int i_ = 0; i_ < 8; ++i_)                                  \
            _Pragma("unroll")                                           \
            for (int j_ = 0; j_ < 4; ++j_)                              \
                acc[i_][j_] = __builtin_amdgcn_mfma_f32_16x16x32_bf16(  \
                    sA[i_], sB[j_], acc[i_][j_], 0, 0, 0);              \
    } while (0)

    // prologue: stage tiles 0,1; wait stage0; read tile0 sub0 frags
    STAGE(0);
    STAGE(1);
    __builtin_amdgcn_sched_barrier(0);
    asm volatile("s_waitcnt vmcnt(8)" ::: "memory");   // stage0's 8 loads landed
    __builtin_amdgcn_sched_barrier(0);
    __builtin_amdgcn_s_barrier();
    __builtin_amdgcn_sched_barrier(0);
    LOADF(fA0, fB0, 0, colx0);

    for (int t = 0; t < 16; ++t) {
        const int bo = (t & 1) * 65536;
        LOADF(fA1, fB1, bo, colx1);        // sub1 frags (used at end of iter)
        MF(fA0, fB0);                      // sub0 (frags loaded last iter; drained)
        __builtin_amdgcn_sched_barrier(0);
        asm volatile("s_waitcnt lgkmcnt(0)" ::: "memory");  // sub1 reads retired
        asm volatile("s_waitcnt vmcnt(0)" ::: "memory");    // stage(t+1) landed
        __builtin_amdgcn_sched_barrier(0);
        __builtin_amdgcn_s_barrier();
        __builtin_amdgcn_sched_barrier(0);
        if (t < 14) STAGE(t + 2);          // overwrite buf[t&1] (reads drained above)
        if (t < 15) LOADF(fA0, fB0, bo ^ 65536, colx0);   // next tile sub0
        MF(fA1, fB1);                      // sub1 (drained pre-barrier)
        __builtin_amdgcn_sched_barrier(0);
    }

#undef STAGE
#undef LOADF
#undef MF

    __syncthreads();

    // ---- epilogue: z = acc + c, h = tanh(z), dot with W21/W22, reduce ----
    const float* cl = cbuf + (size_t)layer * 131072;
    const float* W2 = layer ? W22 : W21;
    float w2v[4];
    #pragma unroll
    for (int j = 0; j < 4; ++j) w2v[j] = W2[n0 + wn * 64 + j * 16 + lr];
    float* red = (float*)smem;   // [256][4]
    #pragma unroll
    for (int i = 0; i < 8; ++i) {
        #pragma unroll
        for (int q = 0; q < 4; ++q) {
            int wrow = wm * 128 + i * 16 + lg * 4 + q;   // 0..255 within M-tile
            int brow = wrow & 127;                        // b index
            float p = 0.f;
            #pragma unroll
            for (int j = 0; j < 4; ++j) {
                int col = n0 + wn * 64 + j * 16 + lr;
                float z = acc[i][j][q] + cl[(size_t)brow * 1024 + col];
                float e = __expf(2.f * z);
                p += (1.f - 2.f / (e + 1.f)) * w2v[j];
            }
            p += __shfl_xor(p, 1);
            p += __shfl_xor(p, 2);
            p += __shfl_xor(p, 4);
            p += __shfl_xor(p, 8);
            if (lr == 0) red[wrow * 4 + wn] = p;
        }
    }
    __syncthreads();
    if (tid < 256) {
        float v = red[tid * 4 + 0] + red[tid * 4 + 1] + red[tid * 4 + 2] + red[tid * 4 + 3];
        sbufp[(size_t)g * M_ROWS + (size_t)mt * 256 + tid] = v;
    }
}

// ---------------- Pass 6: softmax over s -> coef; also zero d_out ----------------
__device__ __forceinline__ float block_max(float v, float* lds) {
    #pragma unroll
    for (int m = 32; m; m >>= 1) v = fmaxf(v, __shfl_xor(v, m));
    if ((threadIdx.x & 63) == 0) lds[threadIdx.x >> 6] = v;
    __syncthreads();
    v = fmaxf(fmaxf(lds[0], lds[1]), fmaxf(lds[2], lds[3]));
    __syncthreads();
    return v;
}
__device__ __forceinline__ float block_sum(float v, float* lds) {
    #pragma unroll
    for (int m = 32; m; m >>= 1) v += __shfl_xor(v, m);
    if ((threadIdx.x & 63) == 0) lds[threadIdx.x >> 6] = v;
    __syncthreads();
    v = lds[0] + lds[1] + lds[2] + lds[3];
    __syncthreads();
    return v;
}

__global__ __launch_bounds__(256) void coef_kernel(const float* __restrict__ sbufp,
                                                   float* __restrict__ coef,
                                                   float* __restrict__ out) {
    __shared__ float lds[4];
    const int b = blockIdx.x, s = threadIdx.x;
    float v1 = 0.f, v2 = 0.f;
    #pragma unroll
    for (int nt = 0; nt < 4; ++nt) {
        v1 += sbufp[(size_t)nt * M_ROWS + (size_t)s * 128 + b];
        v2 += sbufp[(size_t)(4 + nt) * M_ROWS + (size_t)s * 128 + b];
    }
    float m1 = block_max(v1, lds);
    float e1 = expf(v1 - m1);
    float S1 = block_sum(e1, lds);
    float m2 = block_max(v2, lds);
    float e2 = expf(v2 - m2);
    float S2 = block_sum(e2, lds);
    coef[(size_t)s * 128 + b] = (e1 / S1 + e2 / S2) * (0.5f / (float)S_LEN);
    // zero d_out: block b owns row b (1024 floats = 256 float4)
    float4 z4; z4.x = z4.y = z4.z = z4.w = 0.f;
    ((float4*)out)[(size_t)b * 256 + s] = z4;
}

// ---------------- Pass 7: out[b][d] = sum_s coef[s][b] * seq[s][b][d] ----------------
__global__ __launch_bounds__(256) void final_kernel(const float* __restrict__ seq,
                                                    const float* __restrict__ coef,
                                                    float* __restrict__ out) {
    const int b = blockIdx.x, q = blockIdx.y;
    const int d0 = threadIdx.x * 4;
    float4 a; a.x = a.y = a.z = a.w = 0.f;
    for (int si = 0; si < 32; ++si) {
        int s = q * 32 + si;
        float cf = coef[(size_t)s * 128 + b];
        float4 v = *(const float4*)(seq + ((size_t)(s * 128 + b) * 1024 + d0));
        a.x += cf * v.x; a.y += cf * v.y; a.z += cf * v.z; a.w += cf * v.w;
    }
    float* o = out + (size_t)b * 1024 + d0;
    atomicAdd(o + 0, a.x);
    atomicAdd(o + 1, a.y);
    atomicAdd(o + 2, a.z);
    atomicAdd(o + 3, a.w);
}

extern "C" void kernel_launch(void* const* d_in, const int* in_sizes, int n_in,
                              void* d_out, int out_size, void* d_ws, size_t ws_size,
                              hipStream_t stream) {
    const float* feature1 = (const float*)d_in[0];   // [128,1024]
    const float* feature2 = (const float*)d_in[1];   // [128,1024]
    const float* seq      = (const float*)d_in[2];   // [256,128,1024]
    const float* W11      = (const float*)d_in[3];   // [2048,1024]
    const float* b11      = (const float*)d_in[4];
    const float* W12      = (const float*)d_in[5];
    const float* b12      = (const float*)d_in[6];
    const float* W21      = (const float*)d_in[7];   // [1024,1]
    const float* W22      = (const float*)d_in[9];
    float* out = (float*)d_out;

    char* ws = (char*)d_ws;
    unsigned short* Abf   = (unsigned short*)(ws + 0);                  // 67108864 B
    unsigned short* Wt    = (unsigned short*)(ws + 67108864);           //  8388608 B
    unsigned short* fbf   = (unsigned short*)(ws + 75497472);           //   524288 B
    float*          cbuf  = (float*)(ws + 76021760);                    //  1048576 B
    float*          sbufp = (float*)(ws + 77070336);                    //  1048576 B  [8][32768]
    float*          coef  = (float*)(ws + 78118912);                    //   131072 B

    convert_seq<<<2048, 256, 0, stream>>>(seq, Abf, (long)M_ROWS * 1024 / 4);
    convert_f<<<256, 256, 0, stream>>>(feature1, feature2, fbf);
    transpose_w<<<dim3(16, 32, 2), 256, 0, stream>>>(W11, W12, Wt);
    c_precompute<<<dim3(8, 2), 256, 0, stream>>>(fbf, Wt, b11, b12, cbuf);
    fused_main<<<1024, 512, 0, stream>>>(Abf, Wt, cbuf, W21, W22, sbufp);
    coef_kernel<<<128, 256, 0, stream>>>(sbufp, coef, out);
    final_kernel<<<dim3(128, 8), 256, 0, stream>>>(seq, coef, out);
}

// Round 9
// 231.835 us; speedup vs baseline: 1.1303x; 1.1303x over previous
//
#include <hip/hip_runtime.h>

// Problem constants
#define S_LEN 256
#define B_SZ  128
#define M_ROWS (S_LEN * B_SZ)          // 32768

typedef __attribute__((ext_vector_type(8))) short bf16x8;
typedef __attribute__((ext_vector_type(4))) float f32x4;

__device__ __forceinline__ unsigned short f2bf(float x) {
    unsigned u = __float_as_uint(x);
    unsigned r = (u + 0x7fffu + ((u >> 16) & 1u)) >> 16;   // RNE
    return (unsigned short)r;
}

__device__ __forceinline__ void gl_lds16(const void* g, void* l) {
    __builtin_amdgcn_global_load_lds(
        (const __attribute__((address_space(1))) unsigned int*)g,
        (__attribute__((address_space(3))) unsigned int*)l,
        16, 0, 0);
}

// ---------------- Pass 1: seq f32 -> bf16 ----------------
__global__ __launch_bounds__(256) void convert_seq(const float* __restrict__ in,
                                                   unsigned short* __restrict__ out,
                                                   long n4) {
    long i = (long)blockIdx.x * blockDim.x + threadIdx.x;
    long stride = (long)gridDim.x * blockDim.x;
    for (; i < n4; i += stride) {
        float4 v = ((const float4*)in)[i];
        ushort4 o;
        o.x = f2bf(v.x); o.y = f2bf(v.y); o.z = f2bf(v.z); o.w = f2bf(v.w);
        ((ushort4*)out)[i] = o;
    }
}

// ---------------- Pass 2: f1,f2 f32 -> bf16 (layer-major) ----------------
__global__ __launch_bounds__(256) void convert_f(const float* __restrict__ f1,
                                                 const float* __restrict__ f2,
                                                 unsigned short* __restrict__ out) {
    int g = blockIdx.x * 256 + threadIdx.x;            // 0..65535 float4 groups
    float4 v = (g < 32768) ? ((const float4*)f1)[g] : ((const float4*)f2)[g - 32768];
    ushort4 o;
    o.x = f2bf(v.x); o.y = f2bf(v.y); o.z = f2bf(v.z); o.w = f2bf(v.w);
    ((ushort4*)out)[g] = o;
}

// ---------------- Pass 3: W [2048][1024] f32 -> Wt [2][1024][2048] bf16 ----------------
__global__ __launch_bounds__(256) void transpose_w(const float* __restrict__ W11,
                                                   const float* __restrict__ W12,
                                                   unsigned short* __restrict__ Wt) {
    const int nt = blockIdx.x, kt = blockIdx.y, layer = blockIdx.z;
    const float* W = layer ? W12 : W11;
    __shared__ float T[64][65];
    const int c = threadIdx.x & 63, r4 = threadIdx.x >> 6;
    const int k0 = kt * 64, n0 = nt * 64;
    #pragma unroll
    for (int p = 0; p < 16; ++p) {
        int r = p * 4 + r4;
        T[r][c] = W[(size_t)(k0 + r) * 1024 + n0 + c];
    }
    __syncthreads();
    unsigned short* Wl = Wt + (size_t)layer * 1024 * 2048;
    #pragma unroll
    for (int p = 0; p < 16; ++p) {
        int n = p * 4 + r4;
        Wl[(size_t)(n0 + n) * 2048 + k0 + c] = f2bf(T[c][n]);
    }
}

// ---------------- Pass 4: c[layer][b][h] = f@W[1024:] + bias  (MFMA 128x128 tile) ----------------
__global__ __launch_bounds__(256) void c_precompute(const unsigned short* __restrict__ fbf, // [2][128][1024]
                                                    const unsigned short* __restrict__ Wt,  // [2][1024][2048]
                                                    const float* __restrict__ b11,
                                                    const float* __restrict__ b12,
                                                    float* __restrict__ cbuf) {            // [2][128][1024]
    __shared__ char smem[32768];
    unsigned short* ldsA = (unsigned short*)smem;            // [128][64]
    unsigned short* ldsB = (unsigned short*)(smem + 16384);  // [128][64]
    const int n0 = blockIdx.x * 128;
    const int layer = blockIdx.y;
    const int tid = threadIdx.x;
    const int w = tid >> 6, l = tid & 63;
    const int wm = w >> 1, wn = w & 1;
    const int lr = l & 15, lg = l >> 4;
    const unsigned short* Af = fbf + (size_t)layer * 128 * 1024;
    const unsigned short* Wl = Wt + (size_t)layer * 1024 * 2048;
    const float* bias = layer ? b12 : b11;

    f32x4 acc[4][4];
    #pragma unroll
    for (int i = 0; i < 4; ++i)
        #pragma unroll
        for (int j = 0; j < 4; ++j)
            #pragma unroll
            for (int e = 0; e < 4; ++e) acc[i][j][e] = 0.f;

    for (int kk = 0; kk < 1024; kk += 64) {
        __syncthreads();
        #pragma unroll
        for (int c = 0; c < 4; ++c) {
            int o = w * 4096 + c * 1024;
            int ob = o + l * 16;
            int row = ob >> 7, kb = ob & 127;
            gl_lds16((const char*)Af + ((size_t)row * 1024 + kk) * 2 + kb, (char*)ldsA + o);
            gl_lds16((const char*)Wl + ((size_t)(n0 + row) * 2048 + 1024 + kk) * 2 + kb, (char*)ldsB + o);
        }
        __syncthreads();
        #pragma unroll
        for (int ks = 0; ks < 2; ++ks) {
            bf16x8 av[4], bv[4];
            #pragma unroll
            for (int i = 0; i < 4; ++i) {
                av[i] = *(const bf16x8*)(ldsA + (wm * 64 + i * 16 + lr) * 64 + ks * 32 + lg * 8);
                bv[i] = *(const bf16x8*)(ldsB + (wn * 64 + i * 16 + lr) * 64 + ks * 32 + lg * 8);
            }
            #pragma unroll
            for (int i = 0; i < 4; ++i)
                #pragma unroll
                for (int j = 0; j < 4; ++j)
                    acc[i][j] = __builtin_amdgcn_mfma_f32_16x16x32_bf16(av[i], bv[j], acc[i][j], 0, 0, 0);
        }
    }
    float* cl = cbuf + (size_t)layer * 128 * 1024;
    #pragma unroll
    for (int i = 0; i < 4; ++i)
        #pragma unroll
        for (int j = 0; j < 4; ++j)
            #pragma unroll
            for (int q = 0; q < 4; ++q) {
                int rr = wm * 64 + i * 16 + lg * 4 + q;
                int hc = n0 + wn * 64 + j * 16 + lr;
                cl[(size_t)rr * 1024 + hc] = acc[i][j][q] + bias[hc];
            }
}

// ================= Pass 5: main fused GEMM =================
// 256x256 tile, BK=64, 16 waves (wave-tile 64x64), double-buffered LDS
// (2 x 64 KB = 128 KB, 1 blk/CU, 4 waves/SIMD).
// Per K-tile (ONE barrier per 64 K — 16 barriers total, half of R7's 32):
//   { STAGE(t+1 -> buf^1)  (issued early, covered by ~350+ cyc of compute)
//     read 16 frags (both K-slices; compiler interleaves lgkm waits)
//     32 MFMAs
//     sched_barrier | vmcnt(0) | s_barrier }
// LDS tile [256 rows][128 B]; swizzle involution x ^= ((x>>3)&0x70) —
// verified conflict-free (SQ_LDS_BANK_CONFLICT = 0 since R4).
// ks=1 fragment offset = ks=0 offset ^ 64 (bit 6 toggles inside the XOR-safe
// low 7 bits). XCD decode (R8's, FETCH 115 MB): mt ≡ bid (mod 8).

__global__ __launch_bounds__(1024, 4) void fused_main(const unsigned short* __restrict__ Abf, // [32768][1024] bf16
                                                      const unsigned short* __restrict__ Wt,  // [2][1024][2048] bf16
                                                      const float* __restrict__ cbuf,         // [2][128][1024]
                                                      const float* __restrict__ W21,
                                                      const float* __restrict__ W22,
                                                      float* __restrict__ sbufp) {            // [8][32768]
    __shared__ char smem[131072];   // 2 bufs x (A 32K + B 32K)
    const int bid = blockIdx.x;
    const int xcd = bid & 7;
    const int idx = bid >> 3;                    // 0..127
    const int mtq = (idx & 3) + 4 * (idx >> 5);  // 0..15
    const int g   = (idx >> 2) & 7;              // layer*4 + nt
    const int mt  = xcd + 8 * mtq;               // 0..127
    const int layer = g >> 2;
    const int nt    = g & 3;
    const int n0 = nt * 256;

    const int tid = threadIdx.x;
    const int w = tid >> 6, l = tid & 63;
    const int wm = w >> 2, wn = w & 3;  // 4 M-quarters x 4 N-quarters (wave tile 64x64)
    const int lr = l & 15, lg = l >> 4;

    const char* Ag = (const char*)Abf + (size_t)mt * 256 * 2048;                          // row stride 2048 B
    const char* Bg = (const char*)(Wt + (size_t)layer * 1024 * 2048) + (size_t)n0 * 4096; // row stride 4096 B

    // staging: 64 KB per K-tile = 4 gl_lds/thread (A rows 0-127, A rows 128-255,
    // B rows 0-127, B rows 128-255). Linear dest dloc = tid*16 per 16 KB half;
    // global src inverse-swizzled.
    const int dloc = tid * 16;
    const int gsw  = dloc ^ ((dloc >> 3) & 0x70);
    const char* srcA = Ag + (size_t)(gsw >> 7) * 2048 + (gsw & 127);
    const char* srcB = Bg + (size_t)(gsw >> 7) * 4096 + (gsw & 127);
    const int dstT = w * 1024;   // wave-uniform LDS base (HW adds lane*16)

    // fragment LDS offsets (ks=0); ks=1 = offset ^ 64
    const int xr = (lr & 7) << 4;
    int offA[4], offB[4];
    #pragma unroll
    for (int i = 0; i < 4; ++i) {
        offA[i] = (wm * 64 + i * 16 + lr) * 128 + ((lg * 16) ^ xr);
        offB[i] = (wn * 64 + i * 16 + lr) * 128 + ((lg * 16) ^ xr);
    }

    f32x4 acc[4][4];
    #pragma unroll
    for (int i = 0; i < 4; ++i)
        #pragma unroll
        for (int j = 0; j < 4; ++j)
            #pragma unroll
            for (int e = 0; e < 4; ++e) acc[i][j][e] = 0.f;

#define STAGE(t, bi) do {                                               \
        char* d_ = smem + (bi) * 65536;                                 \
        const char* a_ = srcA + (size_t)(t) * 128;                      \
        const char* b_ = srcB + (size_t)(t) * 128;                      \
        gl_lds16(a_,              d_ +         dstT);                   \
        gl_lds16(a_ + 128 * 2048, d_ + 16384 + dstT);                   \
        gl_lds16(b_,              d_ + 32768 + dstT);                   \
        gl_lds16(b_ + 128 * 4096, d_ + 49152 + dstT);                   \
    } while (0)

#define COMPUTE(bi) do {                                                \
        const char* Ab_ = smem + (bi) * 65536;                          \
        const char* Bb_ = Ab_ + 32768;                                  \
        bf16x8 a0_[4], b0_[4], a1_[4], b1_[4];                          \
        _Pragma("unroll")                                               \
        for (int i_ = 0; i_ < 4; ++i_) {                                \
            a0_[i_] = *(const bf16x8*)(Ab_ + offA[i_]);                 \
            b0_[i_] = *(const bf16x8*)(Bb_ + offB[i_]);                 \
            a1_[i_] = *(const bf16x8*)(Ab_ + (offA[i_] ^ 64));          \
            b1_[i_] = *(const bf16x8*)(Bb_ + (offB[i_] ^ 64));          \
        }                                                               \
        _Pragma("unroll")                                               \
        for (int i_ = 0; i_ < 4; ++i_)                                  \
            _Pragma("unroll")                                           \
            for (int j_ = 0; j_ < 4; ++j_)                              \
                acc[i_][j_] = __builtin_amdgcn_mfma_f32_16x16x32_bf16(  \
                    a0_[i_], b0_[j_], acc[i_][j_], 0, 0, 0);            \
        _Pragma("unroll")                                               \
        for (int i_ = 0; i_ < 4; ++i_)                                  \
            _Pragma("unroll")                                           \
            for (int j_ = 0; j_ < 4; ++j_)                              \
                acc[i_][j_] = __builtin_amdgcn_mfma_f32_16x16x32_bf16(  \
                    a1_[i_], b1_[j_], acc[i_][j_], 0, 0, 0);            \
    } while (0)

    // prologue
    STAGE(0, 0);
    __builtin_amdgcn_sched_barrier(0);
    asm volatile("s_waitcnt vmcnt(0)" ::: "memory");
    __builtin_amdgcn_sched_barrier(0);
    __builtin_amdgcn_s_barrier();
    __builtin_amdgcn_sched_barrier(0);

    for (int t = 0; t < 16; ++t) {
        const int cur = t & 1;
        if (t < 15) STAGE(t + 1, cur ^ 1);
        COMPUTE(cur);
        __builtin_amdgcn_sched_barrier(0);
        asm volatile("s_waitcnt vmcnt(0)" ::: "memory");
        __builtin_amdgcn_sched_barrier(0);
        __builtin_amdgcn_s_barrier();
        __builtin_amdgcn_sched_barrier(0);
    }

#undef STAGE
#undef COMPUTE

    // ---- epilogue: z = acc + c, h = tanh(z), dot with W21/W22, reduce ----
    const float* cl = cbuf + (size_t)layer * 131072;
    const float* W2 = layer ? W22 : W21;
    float w2v[4];
    #pragma unroll
    for (int j = 0; j < 4; ++j) w2v[j] = W2[n0 + wn * 64 + j * 16 + lr];
    float* red = (float*)smem;   // [256][4]  (loop's final barrier fences reuse)
    #pragma unroll
    for (int i = 0; i < 4; ++i) {
        #pragma unroll
        for (int q = 0; q < 4; ++q) {
            int wrow = wm * 64 + i * 16 + lg * 4 + q;    // 0..255 within M-tile
            int brow = wrow & 127;                        // b index
            float p = 0.f;
            #pragma unroll
            for (int j = 0; j < 4; ++j) {
                int col = n0 + wn * 64 + j * 16 + lr;
                float z = acc[i][j][q] + cl[(size_t)brow * 1024 + col];
                float e = __expf(2.f * z);
                p += (1.f - 2.f / (e + 1.f)) * w2v[j];
            }
            p += __shfl_xor(p, 1);
            p += __shfl_xor(p, 2);
            p += __shfl_xor(p, 4);
            p += __shfl_xor(p, 8);
            if (lr == 0) red[wrow * 4 + wn] = p;
        }
    }
    __syncthreads();
    if (tid < 256) {
        float v = red[tid * 4 + 0] + red[tid * 4 + 1] + red[tid * 4 + 2] + red[tid * 4 + 3];
        sbufp[(size_t)g * M_ROWS + (size_t)mt * 256 + tid] = v;
    }
}

// ---------------- Pass 6: softmax over s -> coef ----------------
__device__ __forceinline__ float block_max(float v, float* lds) {
    #pragma unroll
    for (int m = 32; m; m >>= 1) v = fmaxf(v, __shfl_xor(v, m));
    if ((threadIdx.x & 63) == 0) lds[threadIdx.x >> 6] = v;
    __syncthreads();
    v = fmaxf(fmaxf(lds[0], lds[1]), fmaxf(lds[2], lds[3]));
    __syncthreads();
    return v;
}
__device__ __forceinline__ float block_sum(float v, float* lds) {
    #pragma unroll
    for (int m = 32; m; m >>= 1) v += __shfl_xor(v, m);
    if ((threadIdx.x & 63) == 0) lds[threadIdx.x >> 6] = v;
    __syncthreads();
    v = lds[0] + lds[1] + lds[2] + lds[3];
    __syncthreads();
    return v;
}

__global__ __launch_bounds__(256) void coef_kernel(const float* __restrict__ sbufp,
                                                   float* __restrict__ coef) {
    __shared__ float lds[4];
    const int b = blockIdx.x, s = threadIdx.x;
    float v1 = 0.f, v2 = 0.f;
    #pragma unroll
    for (int nt = 0; nt < 4; ++nt) {
        v1 += sbufp[(size_t)nt * M_ROWS + (size_t)s * 128 + b];
        v2 += sbufp[(size_t)(4 + nt) * M_ROWS + (size_t)s * 128 + b];
    }
    float m1 = block_max(v1, lds);
    float e1 = expf(v1 - m1);
    float S1 = block_sum(e1, lds);
    float m2 = block_max(v2, lds);
    float e2 = expf(v2 - m2);
    float S2 = block_sum(e2, lds);
    coef[(size_t)s * 128 + b] = (e1 / S1 + e2 / S2) * (0.5f / (float)S_LEN);
}

// ---------------- Pass 7: out[b][d] = sum_s coef[s][b] * seq[s][b][d] ----------------
// Atomic-free: each thread owns one output element, loops all 256 s.
__global__ __launch_bounds__(256) void final_kernel(const float* __restrict__ seq,
                                                    const float* __restrict__ coef,
                                                    float* __restrict__ out) {
    const int b = blockIdx.x, dq = blockIdx.y;
    const int d = dq * 256 + threadIdx.x;
    float a = 0.f;
    #pragma unroll 8
    for (int s = 0; s < 256; ++s) {
        a += coef[(size_t)s * 128 + b] * seq[(size_t)(s * 128 + b) * 1024 + d];
    }
    out[(size_t)b * 1024 + d] = a;
}

extern "C" void kernel_launch(void* const* d_in, const int* in_sizes, int n_in,
                              void* d_out, int out_size, void* d_ws, size_t ws_size,
                              hipStream_t stream) {
    const float* feature1 = (const float*)d_in[0];   // [128,1024]
    const float* feature2 = (const float*)d_in[1];   // [128,1024]
    const float* seq      = (const float*)d_in[2];   // [256,128,1024]
    const float* W11      = (const float*)d_in[3];   // [2048,1024]
    const float* b11      = (const float*)d_in[4];
    const float* W12      = (const float*)d_in[5];
    const float* b12      = (const float*)d_in[6];
    const float* W21      = (const float*)d_in[7];   // [1024,1]
    const float* W22      = (const float*)d_in[9];
    float* out = (float*)d_out;

    char* ws = (char*)d_ws;
    unsigned short* Abf   = (unsigned short*)(ws + 0);                  // 67108864 B
    unsigned short* Wt    = (unsigned short*)(ws + 67108864);           //  8388608 B
    unsigned short* fbf   = (unsigned short*)(ws + 75497472);           //   524288 B
    float*          cbuf  = (float*)(ws + 76021760);                    //  1048576 B
    float*          sbufp = (float*)(ws + 77070336);                    //  1048576 B  [8][32768]
    float*          coef  = (float*)(ws + 78118912);                    //   131072 B

    convert_seq<<<2048, 256, 0, stream>>>(seq, Abf, (long)M_ROWS * 1024 / 4);
    convert_f<<<256, 256, 0, stream>>>(feature1, feature2, fbf);
    transpose_w<<<dim3(16, 32, 2), 256, 0, stream>>>(W11, W12, Wt);
    c_precompute<<<dim3(8, 2), 256, 0, stream>>>(fbf, Wt, b11, b12, cbuf);
    fused_main<<<1024, 1024, 0, stream>>>(Abf, Wt, cbuf, W21, W22, sbufp);
    coef_kernel<<<128, 256, 0, stream>>>(sbufp, coef);
    final_kernel<<<dim3(128, 4), 256, 0, stream>>>(seq, coef, out);
}